// Round 1
// baseline (1298.671 us; speedup 1.0000x reference)
//
#include <hip/hip_runtime.h>
#include <hip/hip_bf16.h>

#define NL 15
#define POS 100
#define NCOL 101
#define EPS 1e-6f

// ---- output offsets (floats) ----
#define O_H    0
#define O_KS   2048
#define SZ_KS  (13*512*256)
#define O_VS   (O_KS + SZ_KS)
#define O_KF   (O_VS + SZ_KS)
#define SZ_KF  (2*1024*256)
#define O_VF   (O_KF + SZ_KF)
#define O_PLE  (O_VF + SZ_KF)
#define O_K13  (O_PLE + 30*256)
#define O_V13  (O_K13 + 512*256)
#define O_K14  (O_V13 + 512*256)
#define O_V14  (O_K14 + 1024*256)

__device__ __forceinline__ float geluf(float x) {
    float x3 = x*x*x;
    return 0.5f*x*(1.f + tanhf(0.7978845608028654f*(x + 0.044715f*x3)));
}

// block = 256 threads (4 waves)
__device__ __forceinline__ float brsum256(float v, float* sred) {
    #pragma unroll
    for (int o=32;o>0;o>>=1) v += __shfl_xor(v,o);
    __syncthreads();
    if ((threadIdx.x&63)==0) sred[threadIdx.x>>6]=v;
    __syncthreads();
    return sred[0]+sred[1]+sred[2]+sred[3];
}
__device__ __forceinline__ float brmax256(float v, float* sred) {
    #pragma unroll
    for (int o=32;o>0;o>>=1) v = fmaxf(v,__shfl_xor(v,o));
    __syncthreads();
    if ((threadIdx.x&63)==0) sred[threadIdx.x>>6]=v;
    __syncthreads();
    return fmaxf(fmaxf(sred[0],sred[1]),fmaxf(sred[2],sred[3]));
}

struct Job {
    const float* W0; const float* W1; const float* W2;
    int N0, N1, N2;
    const float* src0; const float* src1;
    float* out;
    int K; int rows; int ncb; int mode; // 0: rms(src0)*(1+src1); 1: gelu(src0)*src1; 2: gelu(src0); 3: raw src0
};

__global__ __launch_bounds__(256) void gemv_kernel(Job a, Job b, int blocksA) {
    Job j = ((int)blockIdx.x < blocksA) ? a : b;
    int bid = ((int)blockIdx.x < blocksA) ? blockIdx.x : blockIdx.x - blocksA;
    __shared__ float xs[128];
    __shared__ float sred[4];
    int t = threadIdx.x;
    int cb = bid % j.ncb;
    int kc = bid / j.ncb;
    float rs = 1.f;
    if (j.mode == 0) {
        float ss = 0.f;
        for (int i=t;i<j.K;i+=256){ float v=j.src0[i]; ss += v*v; }
        ss = brsum256(ss, sred);
        rs = rsqrtf(ss/(float)j.K + EPS);
    }
    int i0 = kc * j.rows;
    for (int i=t;i<j.rows;i+=256){
        int ii = i0+i; float x;
        if (j.mode==0)      x = j.src0[ii]*rs*(1.f+j.src1[ii]);
        else if (j.mode==1) x = geluf(j.src0[ii])*j.src1[ii];
        else if (j.mode==2) x = geluf(j.src0[ii]);
        else                x = j.src0[ii];
        xs[i] = x;
    }
    __syncthreads();
    int c = cb*1024 + t*4;
    const float* W = nullptr; int lc=0, Nm=0;
    if (c < j.N0) { W=j.W0; lc=c; Nm=j.N0; }
    else if (c < j.N0+j.N1) { W=j.W1; lc=c-j.N0; Nm=j.N1; }
    else if (c < j.N0+j.N1+j.N2) { W=j.W2; lc=c-j.N0-j.N1; Nm=j.N2; }
    if (W) {
        const float* base = W + (size_t)i0*Nm + lc;
        float4 acc = make_float4(0.f,0.f,0.f,0.f);
        for (int r=0;r<j.rows;r++){
            float4 w = *reinterpret_cast<const float4*>(base + (size_t)r*Nm);
            float x = xs[r];
            acc.x += x*w.x; acc.y += x*w.y; acc.z += x*w.z; acc.w += x*w.w;
        }
        atomicAdd(j.out+c+0, acc.x);
        atomicAdd(j.out+c+1, acc.y);
        atomicAdd(j.out+c+2, acc.z);
        atomicAdd(j.out+c+3, acc.w);
    }
}

// proj[p] = dot(ple_conv_w[p,:], h) * 2048^-0.5 ; 4 waves = 4 rows per block
__global__ __launch_bounds__(256) void ple_conv_kernel(const float* __restrict__ Wc,
        const float* __restrict__ h, float* __restrict__ proj) {
    int wid = threadIdx.x >> 6, lane = threadIdx.x & 63;
    int p = blockIdx.x*4 + wid;
    const float4* wr = reinterpret_cast<const float4*>(Wc + (size_t)p*2048);
    const float4* hr = reinterpret_cast<const float4*>(h);
    float acc = 0.f;
    #pragma unroll
    for (int it=0; it<8; it++){
        int idx = it*64 + lane;
        float4 w = wr[idx], x = hr[idx];
        acc += w.x*x.x + w.y*x.y + w.z*x.z + w.w*x.w;
    }
    #pragma unroll
    for (int o=32;o>0;o>>=1) acc += __shfl_xor(acc,o);
    if (lane==0) proj[p] = acc * 0.022097086912079608f;
}

__global__ __launch_bounds__(256) void ple_fin_kernel(const float* __restrict__ proj,
        const float* __restrict__ normw, const float* __restrict__ raw,
        float* __restrict__ outple) {
    __shared__ float sred[4];
    int g = blockIdx.x, t = threadIdx.x;
    float v = proj[g*256+t];
    float ss = brsum256(v*v, sred);
    float rms = rsqrtf(ss*(1.f/256.f) + EPS);
    outple[g*256+t] = (v*rms*normw[t] + raw[g*256+t]) * 0.7071067811865476f;
}

// one block per head; q/k rmsnorm + rope + softmax(cols 0..100) + PV
__global__ __launch_bounds__(256) void attn_kernel(
    const float* __restrict__ qkv,
    const float* __restrict__ wqn, const float* __restrict__ wkn,
    const float* __restrict__ cosv, const float* __restrict__ sinv,
    const float* __restrict__ Kin, const float* __restrict__ Vin,
    float* __restrict__ ctx, float* __restrict__ ksave, float* __restrict__ vsave) {
    __shared__ float qs[256], ksh[256], sc[128], sred[4];
    int t = threadIdx.x, head = blockIdx.x;
    // q: per-head rmsnorm + rope
    float qv = qkv[head*256+t];
    float ss = brsum256(qv*qv, sred);
    float qn = qv * rsqrtf(ss*(1.f/256.f)+EPS) * (1.f+wqn[t]);
    qs[t]=qn; __syncthreads();
    float qr = qn*cosv[t] + ((t<128)? -qs[t+128] : qs[t-128])*sinv[t];
    __syncthreads(); qs[t]=qr;
    // k
    float kv = qkv[2048+t];
    float ks2 = brsum256(kv*kv, sred);
    float kn = kv*rsqrtf(ks2*(1.f/256.f)+EPS)*(1.f+wkn[t]);
    ksh[t]=kn; __syncthreads();
    float kr = kn*cosv[t] + ((t<128)? -ksh[t+128] : ksh[t-128])*sinv[t];
    __syncthreads(); ksh[t]=kr;
    if (head==0){ ksave[t]=kr; vsave[t]=qkv[2304+t]; }
    __syncthreads();
    // scores over active columns 0..100 (mask kills the rest exactly)
    float score = -1e30f;
    if (t < NCOL) {
        float acc=0.f;
        if (t==POS){
            for (int d=0;d<256;d++) acc += qs[d]*ksh[d];
        } else {
            const float4* kr4 = reinterpret_cast<const float4*>(Kin + (size_t)t*256);
            #pragma unroll 8
            for (int d4=0; d4<64; d4++){
                float4 k4 = kr4[d4];
                acc += qs[d4*4]*k4.x + qs[d4*4+1]*k4.y + qs[d4*4+2]*k4.z + qs[d4*4+3]*k4.w;
            }
        }
        score = acc * 0.0625f;
    }
    float mx = brmax256(score, sred);
    float e = (t<NCOL)? expf(score-mx) : 0.f;
    float s = brsum256(e, sred);
    if (t<128) sc[t] = (t<NCOL)? e/s : 0.f;
    __syncthreads();
    float acc=0.f;
    for (int c=0;c<POS;c++) acc += sc[c]*Vin[(size_t)c*256+t];
    acc += sc[POS]*qkv[2304+t];
    ctx[head*256+t]=acc;
}

__device__ __constant__ int SL_LAYER[13] = {0,1,2,3,5,6,7,8,9,10,11,12,13};

// copies all KV caches to d_out with row POS patched; 4 rows / block via float4
__global__ __launch_bounds__(256) void kv_kernel(
    const float* __restrict__ Ksl, const float* __restrict__ Vsl,
    const float* __restrict__ Kfl, const float* __restrict__ Vfl,
    const float* __restrict__ kall, const float* __restrict__ vall,
    float* __restrict__ out) {
    int wid = threadIdx.x>>6, lane = threadIdx.x&63;
    int row = blockIdx.x*4 + wid;
    const float* src; float* dst;
    if (row < 6656) {
        int s = row>>9, r = row&511;
        dst = out + O_KS + (size_t)row*256;
        src = (r==POS) ? kall + SL_LAYER[s]*256 : Ksl + (size_t)row*256;
    } else if (row < 13312) {
        int idx = row-6656; int s=idx>>9, r=idx&511;
        dst = out + O_VS + (size_t)idx*256;
        src = (r==POS) ? vall + SL_LAYER[s]*256 : Vsl + (size_t)idx*256;
    } else if (row < 15360) {
        int idx = row-13312; int f=idx>>10, r=idx&1023;
        dst = out + O_KF + (size_t)idx*256;
        src = (r==POS) ? kall + (f?14:4)*256 : Kfl + (size_t)idx*256;
    } else if (row < 17408) {
        int idx = row-15360; int f=idx>>10, r=idx&1023;
        dst = out + O_VF + (size_t)idx*256;
        src = (r==POS) ? vall + (f?14:4)*256 : Vfl + (size_t)idx*256;
    } else if (row < 17920) {
        int r = row-17408;
        dst = out + O_K13 + (size_t)r*256;
        src = (r==POS) ? kall + 13*256 : Ksl + (size_t)(12*512+r)*256;
    } else if (row < 18432) {
        int r = row-17920;
        dst = out + O_V13 + (size_t)r*256;
        src = (r==POS) ? vall + 13*256 : Vsl + (size_t)(12*512+r)*256;
    } else if (row < 19456) {
        int r = row-18432;
        dst = out + O_K14 + (size_t)r*256;
        src = (r==POS) ? kall + 14*256 : Kfl + (size_t)(1024+r)*256;
    } else {
        int r = row-19456;
        dst = out + O_V14 + (size_t)r*256;
        src = (r==POS) ? vall + 14*256 : Vfl + (size_t)(1024+r)*256;
    }
    float4 v = reinterpret_cast<const float4*>(src)[lane];
    reinterpret_cast<float4*>(dst)[lane] = v;
}

extern "C" void kernel_launch(void* const* d_in, const int* in_sizes, int n_in,
                              void* d_out, int out_size, void* d_ws, size_t ws_size,
                              hipStream_t stream) {
    const float* hidden = (const float*)d_in[0];
    const float* raw    = (const float*)d_in[4];
    const float* cos_s  = (const float*)d_in[5];
    const float* sin_s  = (const float*)d_in[6];
    const float* cos_f  = (const float*)d_in[7];
    const float* sin_f  = (const float*)d_in[8];
    const float* Ksl    = (const float*)d_in[9];
    const float* Vsl    = (const float*)d_in[10];
    const float* Kfl    = (const float*)d_in[11];
    const float* Vfl    = (const float*)d_in[12];
    const float* ple_conv_w = (const float*)d_in[13];
    const float* ple_norm_w = (const float*)d_in[14];
    const float* W_ple  = (const float*)d_in[15];
    const float* Wq     = (const float*)d_in[16];
    const float* Wk     = (const float*)d_in[17];
    const float* Wv     = (const float*)d_in[18];
    const float* Wo     = (const float*)d_in[19];
    const float* w_in   = (const float*)d_in[20];
    const float* w_post = (const float*)d_in[21];
    const float* w_qn   = (const float*)d_in[22];
    const float* w_kn   = (const float*)d_in[23];
    const float* Wg     = (const float*)d_in[24];
    const float* Wu     = (const float*)d_in[25];
    const float* Wd     = (const float*)d_in[26];
    float* out = (float*)d_out;
    float* ws  = (float*)d_ws;

    float* qkv_all = ws;                 // 15*2560 (atomic accum, zeroed)
    float* gu_all  = ws + 38400;         // 15*8192 (atomic accum, zeroed)
    float* ctxb    = ws + 161280;        // 2048
    float* proj    = ws + 163328;        // 7680
    float* kall    = ws + 171008;        // 15*256
    float* vall    = ws + 174848;        // 15*256

    float* hbuf = out + O_H;             // h accumulates in-place in d_out
    float* pleb = out + O_PLE;

    hipMemsetAsync(ws, 0, (size_t)161280*4, stream);
    hipMemcpyAsync(hbuf, hidden, 2048*sizeof(float), hipMemcpyDeviceToDevice, stream);
    ple_conv_kernel<<<1920,256,0,stream>>>(ple_conv_w, hbuf, proj);
    ple_fin_kernel<<<30,256,0,stream>>>(proj, ple_norm_w, raw, pleb);

    Job z = {};
    int si=0, fi=0;
    for (int l=0;l<NL;l++){
        bool full = (l==4)||(l==14);
        const float* cv = full? cos_f: cos_s;
        const float* sv = full? sin_f: sin_s;
        const float* Kin = full? Kfl + (size_t)fi*1024*256 : Ksl + (size_t)si*512*256;
        const float* Vin = full? Vfl + (size_t)fi*1024*256 : Vsl + (size_t)si*512*256;
        float* qkv = qkv_all + l*2560;
        float* gu  = gu_all + l*8192;

        Job jq;
        jq.W0 = Wq + (size_t)l*2048*2048; jq.N0 = 2048;
        jq.W1 = Wk + (size_t)l*2048*256;  jq.N1 = 256;
        jq.W2 = Wv + (size_t)l*2048*256;  jq.N2 = 256;
        jq.src0 = hbuf; jq.src1 = w_in + l*2048;
        jq.out = qkv; jq.K = 2048; jq.rows = 32; jq.ncb = 3; jq.mode = 0;
        int gq = 3*(2048/32);
        gemv_kernel<<<gq,256,0,stream>>>(jq, z, gq);

        attn_kernel<<<8,256,0,stream>>>(qkv, w_qn+l*256, w_kn+l*256, cv, sv,
                                        Kin, Vin, ctxb, kall+l*256, vall+l*256);

        Job jo;
        jo.W0 = Wo + (size_t)l*2048*2048; jo.N0=2048; jo.W1=nullptr; jo.N1=0; jo.W2=nullptr; jo.N2=0;
        jo.src0 = ctxb; jo.src1=nullptr; jo.out = hbuf; jo.K=2048; jo.rows=32; jo.ncb=2; jo.mode=3;
        int go = 2*(2048/32);
        gemv_kernel<<<go,256,0,stream>>>(jo, z, go);

        Job jg;
        jg.W0 = Wg + (size_t)l*2048*4096; jg.N0=4096;
        jg.W1 = Wu + (size_t)l*2048*4096; jg.N1=4096; jg.W2=nullptr; jg.N2=0;
        jg.src0=hbuf; jg.src1=w_post+l*2048; jg.out=gu; jg.K=2048; jg.rows=64; jg.ncb=8; jg.mode=0;
        int gg = 8*(2048/64);
        gemv_kernel<<<gg,256,0,stream>>>(jg, z, gg);

        Job jd;
        jd.W0 = Wd + (size_t)l*4096*2048; jd.N0=2048; jd.W1=nullptr; jd.N1=0; jd.W2=nullptr; jd.N2=0;
        jd.src0=gu; jd.src1=gu+4096; jd.out=hbuf; jd.K=4096; jd.rows=32; jd.ncb=2; jd.mode=1;
        int gd = 2*(4096/32);
        Job jp;
        jp.W0 = W_ple + (size_t)l*256*2048; jp.N0=2048; jp.W1=nullptr; jp.N1=0; jp.W2=nullptr; jp.N2=0;
        jp.src0=pleb + l*256; jp.src1=nullptr; jp.out=hbuf; jp.K=256; jp.rows=64; jp.ncb=2; jp.mode=2;
        int gp = 2*(256/64);
        gemv_kernel<<<gd+gp,256,0,stream>>>(jd, jp, gd);

        if (full) fi++; else si++;
    }
    kv_kernel<<<5120,256,0,stream>>>(Ksl, Vsl, Kfl, Vfl, kall, vall, out);
}